// Round 1
// baseline (569.394 us; speedup 1.0000x reference)
//
#include <hip/hip_runtime.h>

#define NN 100000      // nodes
#define NE 1600000     // edges
#define NF 128         // in features
#define NH 64          // hidden
#define NC 40          // classes

// ---------------- CSR build ----------------

__global__ void count_kernel(const int* __restrict__ col, int* __restrict__ cnt) {
    int e = blockIdx.x * blockDim.x + threadIdx.x;
    if (e < NE) atomicAdd(&cnt[col[e]], 1);
}

__global__ void dinv_kernel(const int* __restrict__ cnt, float* __restrict__ dinv) {
    int i = blockIdx.x * blockDim.x + threadIdx.x;
    if (i < NN) dinv[i] = rsqrtf((float)(cnt[i] + 1));   // +1 self loop, always > 0
}

// scanA: each block scans 1024 elements (256 threads x int4), writes block-local
// exclusive scan into rowptr and the block total into bsums.
__global__ __launch_bounds__(256) void scanA(const int* __restrict__ cnt,
                                             int* __restrict__ rowptr,
                                             int* __restrict__ bsums) {
    __shared__ int wsum[4];
    int tid  = threadIdx.x;
    int base = blockIdx.x * 1024 + tid * 4;
    int4 v = make_int4(0, 0, 0, 0);
    if (base < NN) v = *(const int4*)(cnt + base);   // NN % 4 == 0, so all-or-none
    int ts = v.x + v.y + v.z + v.w;
    int x = ts;
    #pragma unroll
    for (int d = 1; d < 64; d <<= 1) {
        int n = __shfl_up(x, d, 64);
        if ((tid & 63) >= d) x += n;
    }
    int wid = tid >> 6, lane = tid & 63;
    if (lane == 63) wsum[wid] = x;
    __syncthreads();
    int woff = 0;
    for (int w = 0; w < wid; ++w) woff += wsum[w];
    int excl = woff + x - ts;
    if (base < NN) {
        int4 o;
        o.x = excl;
        o.y = excl + v.x;
        o.z = excl + v.x + v.y;
        o.w = excl + v.x + v.y + v.z;
        *(int4*)(rowptr + base) = o;
    }
    if (tid == 0) bsums[blockIdx.x] = wsum[0] + wsum[1] + wsum[2] + wsum[3];
}

// scanB: single block, exclusive scan of block sums (nb <= 128)
__global__ __launch_bounds__(128) void scanB(int* __restrict__ bsums, int nb) {
    __shared__ int s[128];
    int t = threadIdx.x;
    int v = (t < nb) ? bsums[t] : 0;
    s[t] = v;
    __syncthreads();
    for (int d = 1; d < 128; d <<= 1) {
        int add = (t >= d) ? s[t - d] : 0;
        __syncthreads();
        s[t] += add;
        __syncthreads();
    }
    if (t < nb) bsums[t] = s[t] - v;   // exclusive
}

// scanC: add block offsets; also init cursor = rowptr
__global__ __launch_bounds__(256) void scanC(int* __restrict__ rowptr,
                                             int* __restrict__ cursor,
                                             const int* __restrict__ bsums) {
    int base = blockIdx.x * 1024 + threadIdx.x * 4;
    if (base < NN) {
        int off = bsums[blockIdx.x];
        int4 v = *(int4*)(rowptr + base);
        v.x += off; v.y += off; v.z += off; v.w += off;
        *(int4*)(rowptr + base) = v;
        *(int4*)(cursor + base) = v;
    }
}

__global__ void scatter_kernel(const int* __restrict__ row, const int* __restrict__ col,
                               int* __restrict__ cursor, int* __restrict__ csr) {
    int e = blockIdx.x * blockDim.x + threadIdx.x;
    if (e < NE) {
        int c = col[e];
        int pos = atomicAdd(&cursor[c], 1);
        csr[pos] = row[e];
    }
}

// ---------------- dense ops ----------------

// out[r][f] = (X[r] . W[:,f]) * dinv[r]    for f in [0,64)
// block: 256 threads = 4 waves, wave handles 4 rows; W staged in LDS.
template <int K>
__global__ __launch_bounds__(256) void gemm_scaled(const float* __restrict__ X,
                                                   const float* __restrict__ W,
                                                   const float* __restrict__ dinv,
                                                   float* __restrict__ out) {
    __shared__ float Wl[K * NH];
    int tid = threadIdx.x;
    for (int i = tid; i < K * NH / 4; i += 256)
        ((float4*)Wl)[i] = ((const float4*)W)[i];
    __syncthreads();
    int wid = tid >> 6, lane = tid & 63;
    int rbase = blockIdx.x * 16 + wid * 4;           // 6250 blocks * 16 rows = NN exactly
    const float4* xr0 = (const float4*)(X + (size_t)(rbase + 0) * K);
    const float4* xr1 = (const float4*)(X + (size_t)(rbase + 1) * K);
    const float4* xr2 = (const float4*)(X + (size_t)(rbase + 2) * K);
    const float4* xr3 = (const float4*)(X + (size_t)(rbase + 3) * K);
    float acc0 = 0.f, acc1 = 0.f, acc2 = 0.f, acc3 = 0.f;
    #pragma unroll 4
    for (int k4 = 0; k4 < K / 4; ++k4) {
        float w0 = Wl[(k4 * 4 + 0) * NH + lane];
        float w1 = Wl[(k4 * 4 + 1) * NH + lane];
        float w2 = Wl[(k4 * 4 + 2) * NH + lane];
        float w3 = Wl[(k4 * 4 + 3) * NH + lane];
        float4 a0 = xr0[k4], a1 = xr1[k4], a2 = xr2[k4], a3 = xr3[k4];
        acc0 = fmaf(a0.w, w3, fmaf(a0.z, w2, fmaf(a0.y, w1, fmaf(a0.x, w0, acc0))));
        acc1 = fmaf(a1.w, w3, fmaf(a1.z, w2, fmaf(a1.y, w1, fmaf(a1.x, w0, acc1))));
        acc2 = fmaf(a2.w, w3, fmaf(a2.z, w2, fmaf(a2.y, w1, fmaf(a2.x, w0, acc2))));
        acc3 = fmaf(a3.w, w3, fmaf(a3.z, w2, fmaf(a3.y, w1, fmaf(a3.x, w0, acc3))));
    }
    out[(size_t)(rbase + 0) * NH + lane] = acc0 * dinv[rbase + 0];
    out[(size_t)(rbase + 1) * NH + lane] = acc1 * dinv[rbase + 1];
    out[(size_t)(rbase + 2) * NH + lane] = acc2 * dinv[rbase + 2];
    out[(size_t)(rbase + 3) * NH + lane] = acc3 * dinv[rbase + 3];
}

// aggregation: wave per destination node, lane = feature.
// out[c] = relu(dinv[c] * (hs[c] + sum_{r in in(c)} hs[r]) + bias)
__global__ __launch_bounds__(256) void aggregate(const float* __restrict__ hs,
                                                 const int* __restrict__ rowptr,
                                                 const int* __restrict__ rowend,
                                                 const int* __restrict__ csr,
                                                 const float* __restrict__ dinv,
                                                 const float* __restrict__ bias,
                                                 float* __restrict__ out) {
    int wid = threadIdx.x >> 6, lane = threadIdx.x & 63;
    int node = blockIdx.x * 4 + wid;
    if (node >= NN) return;
    float acc = hs[(size_t)node * NH + lane];        // self loop
    int e = rowptr[node], end = rowend[node];
    for (; e + 4 <= end; e += 4) {
        int r0 = csr[e + 0], r1 = csr[e + 1], r2 = csr[e + 2], r3 = csr[e + 3];
        float v0 = hs[(size_t)r0 * NH + lane];
        float v1 = hs[(size_t)r1 * NH + lane];
        float v2 = hs[(size_t)r2 * NH + lane];
        float v3 = hs[(size_t)r3 * NH + lane];
        acc += v0; acc += v1; acc += v2; acc += v3;
    }
    for (; e < end; ++e) acc += hs[(size_t)csr[e] * NH + lane];
    float v = fmaf(acc, dinv[node], bias[lane]);
    out[(size_t)node * NH + lane] = fmaxf(v, 0.f);
}

// out[r][c] = H[r] . Wc[:,c] + bc[c]  (no relu), c in [0,40)
__global__ __launch_bounds__(256) void gemm_out(const float* __restrict__ H,
                                                const float* __restrict__ Wc,
                                                const float* __restrict__ bc,
                                                float* __restrict__ out) {
    __shared__ float Wl[NH * NC];
    __shared__ float bl[NC];
    int tid = threadIdx.x;
    for (int i = tid; i < NH * NC; i += 256) Wl[i] = Wc[i];
    if (tid < NC) bl[tid] = bc[tid];
    __syncthreads();
    int wid = tid >> 6, lane = tid & 63;
    int rbase = blockIdx.x * 16 + wid * 4;
    const float4* h0 = (const float4*)(H + (size_t)(rbase + 0) * NH);
    const float4* h1 = (const float4*)(H + (size_t)(rbase + 1) * NH);
    const float4* h2 = (const float4*)(H + (size_t)(rbase + 2) * NH);
    const float4* h3 = (const float4*)(H + (size_t)(rbase + 3) * NH);
    if (lane < NC) {
        float acc0 = 0.f, acc1 = 0.f, acc2 = 0.f, acc3 = 0.f;
        #pragma unroll 4
        for (int k4 = 0; k4 < NH / 4; ++k4) {
            float w0 = Wl[(k4 * 4 + 0) * NC + lane];
            float w1 = Wl[(k4 * 4 + 1) * NC + lane];
            float w2 = Wl[(k4 * 4 + 2) * NC + lane];
            float w3 = Wl[(k4 * 4 + 3) * NC + lane];
            float4 a0 = h0[k4], a1 = h1[k4], a2 = h2[k4], a3 = h3[k4];
            acc0 = fmaf(a0.w, w3, fmaf(a0.z, w2, fmaf(a0.y, w1, fmaf(a0.x, w0, acc0))));
            acc1 = fmaf(a1.w, w3, fmaf(a1.z, w2, fmaf(a1.y, w1, fmaf(a1.x, w0, acc1))));
            acc2 = fmaf(a2.w, w3, fmaf(a2.z, w2, fmaf(a2.y, w1, fmaf(a2.x, w0, acc2))));
            acc3 = fmaf(a3.w, w3, fmaf(a3.z, w2, fmaf(a3.y, w1, fmaf(a3.x, w0, acc3))));
        }
        out[(size_t)(rbase + 0) * NC + lane] = acc0 + bl[lane];
        out[(size_t)(rbase + 1) * NC + lane] = acc1 + bl[lane];
        out[(size_t)(rbase + 2) * NC + lane] = acc2 + bl[lane];
        out[(size_t)(rbase + 3) * NC + lane] = acc3 + bl[lane];
    }
}

// ---------------- launch ----------------

extern "C" void kernel_launch(void* const* d_in, const int* in_sizes, int n_in,
                              void* d_out, int out_size, void* d_ws, size_t ws_size,
                              hipStream_t stream) {
    const float* x  = (const float*)d_in[0];
    const int* ei   = (const int*)d_in[1];      // [2, NE], int32
    const int* row  = ei;
    const int* col  = ei + NE;
    const float* W1 = (const float*)d_in[2];
    const float* b1 = (const float*)d_in[3];
    const float* W2 = (const float*)d_in[4];
    const float* b2 = (const float*)d_in[5];
    const float* Wc = (const float*)d_in[6];
    const float* bc = (const float*)d_in[7];
    float* out = (float*)d_out;

    char* ws = (char*)d_ws;
    size_t off = 0;
    auto alloc = [&](size_t bytes) {
        void* p = ws + off;
        off = (off + bytes + 255) & ~(size_t)255;
        return p;
    };
    int*   cnt    = (int*)alloc((size_t)NN * 4);
    float* dinv   = (float*)alloc((size_t)NN * 4);
    int*   rowptr = (int*)alloc((size_t)NN * 4);
    int*   cursor = (int*)alloc((size_t)NN * 4);
    int*   bsums  = (int*)alloc(512);
    int*   csr    = (int*)alloc((size_t)NE * 4);
    float* bufA   = (float*)alloc((size_t)NN * NH * 4);
    float* bufB   = (float*)alloc((size_t)NN * NH * 4);

    const int NB = (NN + 1023) / 1024;           // 98

    hipMemsetAsync(cnt, 0, (size_t)NN * 4, stream);
    count_kernel<<<(NE + 255) / 256, 256, 0, stream>>>(col, cnt);
    dinv_kernel<<<(NN + 255) / 256, 256, 0, stream>>>(cnt, dinv);
    scanA<<<NB, 256, 0, stream>>>(cnt, rowptr, bsums);
    scanB<<<1, 128, 0, stream>>>(bsums, NB);
    scanC<<<NB, 256, 0, stream>>>(rowptr, cursor, bsums);
    scatter_kernel<<<(NE + 255) / 256, 256, 0, stream>>>(row, col, cursor, csr);

    // layer 1: hs = (x @ W1) * dinv ; h1 = relu(dinv * agg + b1)
    gemm_scaled<NF><<<NN / 16, 256, 0, stream>>>(x, W1, dinv, bufA);
    aggregate<<<(NN + 3) / 4, 256, 0, stream>>>(bufA, rowptr, cursor, csr, dinv, b1, bufB);
    // layer 2
    gemm_scaled<NH><<<NN / 16, 256, 0, stream>>>(bufB, W2, dinv, bufA);
    aggregate<<<(NN + 3) / 4, 256, 0, stream>>>(bufA, rowptr, cursor, csr, dinv, b2, bufB);
    // classifier
    gemm_out<<<NN / 16, 256, 0, stream>>>(bufB, Wc, bc, out);
}

// Round 2
// 400.069 us; speedup vs baseline: 1.4232x; 1.4232x over previous
//
#include <hip/hip_runtime.h>

#define NN 100000      // nodes
#define NE 1600000     // edges
#define NF 128         // in features
#define NH 64          // hidden
#define NC 40          // classes

// ---------------- CSR build ----------------

__global__ void count_kernel(const int* __restrict__ col, int* __restrict__ cnt) {
    int t = blockIdx.x * blockDim.x + threadIdx.x;   // NE/4 threads
    if (t * 4 < NE) {
        int4 c = ((const int4*)col)[t];
        atomicAdd(&cnt[c.x], 1);
        atomicAdd(&cnt[c.y], 1);
        atomicAdd(&cnt[c.z], 1);
        atomicAdd(&cnt[c.w], 1);
    }
}

// scanA: each block scans 1024 elements (256 threads x int4), writes block-local
// exclusive scan into rowptr and the block total into bsums. Also emits dinv.
__global__ __launch_bounds__(256) void scanA(const int* __restrict__ cnt,
                                             int* __restrict__ rowptr,
                                             int* __restrict__ bsums,
                                             float* __restrict__ dinv) {
    __shared__ int wsum[4];
    int tid  = threadIdx.x;
    int base = blockIdx.x * 1024 + tid * 4;
    int4 v = make_int4(0, 0, 0, 0);
    if (base < NN) v = *(const int4*)(cnt + base);   // NN % 4 == 0, so all-or-none
    int ts = v.x + v.y + v.z + v.w;
    int x = ts;
    #pragma unroll
    for (int d = 1; d < 64; d <<= 1) {
        int n = __shfl_up(x, d, 64);
        if ((tid & 63) >= d) x += n;
    }
    int wid = tid >> 6, lane = tid & 63;
    if (lane == 63) wsum[wid] = x;
    __syncthreads();
    int woff = 0;
    for (int w = 0; w < wid; ++w) woff += wsum[w];
    int excl = woff + x - ts;
    if (base < NN) {
        int4 o;
        o.x = excl;
        o.y = excl + v.x;
        o.z = excl + v.x + v.y;
        o.w = excl + v.x + v.y + v.z;
        *(int4*)(rowptr + base) = o;
        float4 dv;
        dv.x = rsqrtf((float)(v.x + 1));             // +1 self loop, always > 0
        dv.y = rsqrtf((float)(v.y + 1));
        dv.z = rsqrtf((float)(v.z + 1));
        dv.w = rsqrtf((float)(v.w + 1));
        *(float4*)(dinv + base) = dv;
    }
    if (tid == 0) bsums[blockIdx.x] = wsum[0] + wsum[1] + wsum[2] + wsum[3];
}

// scanB: single block, exclusive scan of block sums (nb <= 128)
__global__ __launch_bounds__(128) void scanB(int* __restrict__ bsums, int nb) {
    __shared__ int s[128];
    int t = threadIdx.x;
    int v = (t < nb) ? bsums[t] : 0;
    s[t] = v;
    __syncthreads();
    for (int d = 1; d < 128; d <<= 1) {
        int add = (t >= d) ? s[t - d] : 0;
        __syncthreads();
        s[t] += add;
        __syncthreads();
    }
    if (t < nb) bsums[t] = s[t] - v;   // exclusive
}

// scanC: add block offsets; also init cursor = rowptr
__global__ __launch_bounds__(256) void scanC(int* __restrict__ rowptr,
                                             int* __restrict__ cursor,
                                             const int* __restrict__ bsums) {
    int base = blockIdx.x * 1024 + threadIdx.x * 4;
    if (base < NN) {
        int off = bsums[blockIdx.x];
        int4 v = *(int4*)(rowptr + base);
        v.x += off; v.y += off; v.z += off; v.w += off;
        *(int4*)(rowptr + base) = v;
        *(int4*)(cursor + base) = v;
    }
}

__global__ void scatter_kernel(const int* __restrict__ row, const int* __restrict__ col,
                               int* __restrict__ cursor, int* __restrict__ csr) {
    int t = blockIdx.x * blockDim.x + threadIdx.x;   // NE/4 threads
    if (t * 4 < NE) {
        int4 c = ((const int4*)col)[t];
        int4 r = ((const int4*)row)[t];
        int p0 = atomicAdd(&cursor[c.x], 1);
        int p1 = atomicAdd(&cursor[c.y], 1);
        int p2 = atomicAdd(&cursor[c.z], 1);
        int p3 = atomicAdd(&cursor[c.w], 1);
        csr[p0] = r.x;
        csr[p1] = r.y;
        csr[p2] = r.z;
        csr[p3] = r.w;
    }
}

// ---------------- tiled fp32 GEMM ----------------
// Block: 64 rows x N cols. 256 threads as 16x16; each thread owns 4 rows x 4 cols.
// EPI==0: out[r][c] = acc * aux[r]          (aux = dinv, pre-scale for aggregation)
// EPI==1: out[r][c] = acc + aux[c]          (aux = bias, classifier)
template <int K, int N, int EPI>
__global__ __launch_bounds__(256) void gemm_tiled(const float* __restrict__ X,
                                                  const float* __restrict__ W,
                                                  const float* __restrict__ aux,
                                                  float* __restrict__ out) {
    constexpr int KT  = 64;          // K tile
    constexpr int KTP = KT + 4;      // padded floats per X row (keeps 16B align, breaks bank stride)
    __shared__ float Xl[64 * KTP];
    __shared__ float Wl[KT * N + 64];          // +64 slack: N=40 dead-lane reads stay in-bounds
    int tid = threadIdx.x;
    int tr = tid >> 4, tc = tid & 15;
    int rbase = blockIdx.x * 64;
    float4 acc[4] = {};

    for (int kt = 0; kt < K; kt += KT) {
        // stage X tile: 64 rows x KT cols = 1024 float4, 4 per thread
        int fid = tid;
        #pragma unroll
        for (int p = 0; p < 4; ++p, fid += 256) {
            int m = fid >> 4, k4 = fid & 15;
            int rr = rbase + m; if (rr >= NN) rr = NN - 1;   // clamp (stores guarded)
            float4 v = *(const float4*)(X + (size_t)rr * K + kt + k4 * 4);
            *(float4*)(Xl + m * KTP + k4 * 4) = v;
        }
        // stage W tile: rows kt..kt+KT, all N cols
        constexpr int NW4 = KT * N / 4;
        for (int f = tid; f < NW4; f += 256)
            ((float4*)Wl)[f] = *((const float4*)(W + (size_t)kt * N) + f);
        __syncthreads();

        #pragma unroll 2
        for (int k4 = 0; k4 < KT / 4; ++k4) {
            float4 xa[4], wa[4];
            #pragma unroll
            for (int i = 0; i < 4; ++i)
                xa[i] = *(const float4*)(Xl + (tr * 4 + i) * KTP + k4 * 4);
            #pragma unroll
            for (int j = 0; j < 4; ++j)
                wa[j] = *(const float4*)(Wl + (k4 * 4 + j) * N + tc * 4);
            #pragma unroll
            for (int i = 0; i < 4; ++i) {
                acc[i].x = fmaf(xa[i].x, wa[0].x, acc[i].x);
                acc[i].y = fmaf(xa[i].x, wa[0].y, acc[i].y);
                acc[i].z = fmaf(xa[i].x, wa[0].z, acc[i].z);
                acc[i].w = fmaf(xa[i].x, wa[0].w, acc[i].w);
                acc[i].x = fmaf(xa[i].y, wa[1].x, acc[i].x);
                acc[i].y = fmaf(xa[i].y, wa[1].y, acc[i].y);
                acc[i].z = fmaf(xa[i].y, wa[1].z, acc[i].z);
                acc[i].w = fmaf(xa[i].y, wa[1].w, acc[i].w);
                acc[i].x = fmaf(xa[i].z, wa[2].x, acc[i].x);
                acc[i].y = fmaf(xa[i].z, wa[2].y, acc[i].y);
                acc[i].z = fmaf(xa[i].z, wa[2].z, acc[i].z);
                acc[i].w = fmaf(xa[i].z, wa[2].w, acc[i].w);
                acc[i].x = fmaf(xa[i].w, wa[3].x, acc[i].x);
                acc[i].y = fmaf(xa[i].w, wa[3].y, acc[i].y);
                acc[i].z = fmaf(xa[i].w, wa[3].z, acc[i].z);
                acc[i].w = fmaf(xa[i].w, wa[3].w, acc[i].w);
            }
        }
        __syncthreads();
    }

    if (EPI == 0) {
        #pragma unroll
        for (int i = 0; i < 4; ++i) {
            int r = rbase + tr * 4 + i;
            if (r < NN) {
                float d = aux[r];
                float4 v = acc[i];
                v.x *= d; v.y *= d; v.z *= d; v.w *= d;
                *(float4*)(out + (size_t)r * N + tc * 4) = v;
            }
        }
    } else {
        if (tc * 4 < N) {
            float4 b = *(const float4*)(aux + tc * 4);
            #pragma unroll
            for (int i = 0; i < 4; ++i) {
                int r = rbase + tr * 4 + i;
                if (r < NN) {
                    float4 v = acc[i];
                    v.x += b.x; v.y += b.y; v.z += b.z; v.w += b.w;
                    *(float4*)(out + (size_t)r * N + tc * 4) = v;
                }
            }
        }
    }
}

// ---------------- aggregation ----------------
// wave per destination node. Lane split: sg = lane>>4 (4 subgroups), sl = lane&15.
// Each subgroup gathers a different edge's full 256B row via float4 (1KB per wave instr).
// out[c] = relu(dinv[c] * (hs[c] + sum_{r in in(c)} hs[r]) + bias)
__global__ __launch_bounds__(256) void aggregate(const float* __restrict__ hs,
                                                 const int* __restrict__ rowptr,
                                                 const int* __restrict__ rowend,
                                                 const int* __restrict__ csr,
                                                 const float* __restrict__ dinv,
                                                 const float* __restrict__ bias,
                                                 float* __restrict__ out) {
    int wid = threadIdx.x >> 6, lane = threadIdx.x & 63;
    int sg = lane >> 4, sl = lane & 15;
    int node = blockIdx.x * 4 + wid;
    if (node >= NN) return;
    const float4* hs4 = (const float4*)hs;           // row = 16 float4
    float4 acc = make_float4(0.f, 0.f, 0.f, 0.f);
    float4 acc2 = make_float4(0.f, 0.f, 0.f, 0.f);
    if (sg == 0) acc = hs4[(size_t)node * 16 + sl];  // self loop
    int e = rowptr[node], end = rowend[node];
    for (; e + 8 <= end; e += 8) {
        int r0 = csr[e + sg];
        int r1 = csr[e + 4 + sg];
        float4 v0 = hs4[(size_t)r0 * 16 + sl];
        float4 v1 = hs4[(size_t)r1 * 16 + sl];
        acc.x += v0.x; acc.y += v0.y; acc.z += v0.z; acc.w += v0.w;
        acc2.x += v1.x; acc2.y += v1.y; acc2.z += v1.z; acc2.w += v1.w;
    }
    if (e + 4 <= end) {
        int r = csr[e + sg];
        float4 v = hs4[(size_t)r * 16 + sl];
        acc.x += v.x; acc.y += v.y; acc.z += v.z; acc.w += v.w;
        e += 4;
    }
    if (e + sg < end) {
        int r = csr[e + sg];
        float4 v = hs4[(size_t)r * 16 + sl];
        acc.x += v.x; acc.y += v.y; acc.z += v.z; acc.w += v.w;
    }
    acc.x += acc2.x; acc.y += acc2.y; acc.z += acc2.z; acc.w += acc2.w;
    // reduce across the 4 subgroups (lanes with equal sl)
    acc.x += __shfl_xor(acc.x, 16); acc.y += __shfl_xor(acc.y, 16);
    acc.z += __shfl_xor(acc.z, 16); acc.w += __shfl_xor(acc.w, 16);
    acc.x += __shfl_xor(acc.x, 32); acc.y += __shfl_xor(acc.y, 32);
    acc.z += __shfl_xor(acc.z, 32); acc.w += __shfl_xor(acc.w, 32);
    if (sg == 0) {
        float d = dinv[node];
        float4 b = *(const float4*)(bias + sl * 4);
        float4 v;
        v.x = fmaxf(fmaf(acc.x, d, b.x), 0.f);
        v.y = fmaxf(fmaf(acc.y, d, b.y), 0.f);
        v.z = fmaxf(fmaf(acc.z, d, b.z), 0.f);
        v.w = fmaxf(fmaf(acc.w, d, b.w), 0.f);
        ((float4*)out)[(size_t)node * 16 + sl] = v;
    }
}

// ---------------- launch ----------------

extern "C" void kernel_launch(void* const* d_in, const int* in_sizes, int n_in,
                              void* d_out, int out_size, void* d_ws, size_t ws_size,
                              hipStream_t stream) {
    const float* x  = (const float*)d_in[0];
    const int* ei   = (const int*)d_in[1];      // [2, NE], int32
    const int* row  = ei;
    const int* col  = ei + NE;
    const float* W1 = (const float*)d_in[2];
    const float* b1 = (const float*)d_in[3];
    const float* W2 = (const float*)d_in[4];
    const float* b2 = (const float*)d_in[5];
    const float* Wc = (const float*)d_in[6];
    const float* bc = (const float*)d_in[7];
    float* out = (float*)d_out;

    char* ws = (char*)d_ws;
    size_t off = 0;
    auto alloc = [&](size_t bytes) {
        void* p = ws + off;
        off = (off + bytes + 255) & ~(size_t)255;
        return p;
    };
    int*   cnt    = (int*)alloc((size_t)NN * 4);
    float* dinv   = (float*)alloc((size_t)NN * 4);
    int*   rowptr = (int*)alloc((size_t)NN * 4);
    int*   cursor = (int*)alloc((size_t)NN * 4);
    int*   bsums  = (int*)alloc(512);
    int*   csr    = (int*)alloc((size_t)NE * 4);
    float* bufA   = (float*)alloc((size_t)NN * NH * 4);
    float* bufB   = (float*)alloc((size_t)NN * NH * 4);

    const int NB = (NN + 1023) / 1024;           // 98
    const int GB = (NN + 63) / 64;               // 1563

    hipMemsetAsync(cnt, 0, (size_t)NN * 4, stream);
    count_kernel<<<(NE / 4 + 255) / 256, 256, 0, stream>>>(col, cnt);
    scanA<<<NB, 256, 0, stream>>>(cnt, rowptr, bsums, dinv);
    scanB<<<1, 128, 0, stream>>>(bsums, NB);
    scanC<<<NB, 256, 0, stream>>>(rowptr, cursor, bsums);
    scatter_kernel<<<(NE / 4 + 255) / 256, 256, 0, stream>>>(row, col, cursor, csr);

    // layer 1: hs = (x @ W1) * dinv ; h1 = relu(dinv * agg + b1)
    gemm_tiled<NF, NH, 0><<<GB, 256, 0, stream>>>(x, W1, dinv, bufA);
    aggregate<<<(NN + 3) / 4, 256, 0, stream>>>(bufA, rowptr, cursor, csr, dinv, b1, bufB);
    // layer 2
    gemm_tiled<NH, NH, 0><<<GB, 256, 0, stream>>>(bufB, W2, dinv, bufA);
    aggregate<<<(NN + 3) / 4, 256, 0, stream>>>(bufA, rowptr, cursor, csr, dinv, b2, bufB);
    // classifier
    gemm_tiled<NH, NC, 1><<<GB, 256, 0, stream>>>(bufB, Wc, bc, out);
}

// Round 3
// 245.533 us; speedup vs baseline: 2.3190x; 1.6294x over previous
//
#include <hip/hip_runtime.h>

#define NN 100000      // nodes
#define NE 1600000     // edges
#define NF 128         // in features
#define NH 64          // hidden
#define NC 40          // classes

#define BKN 256                      // nodes per bucket
#define NBK ((NN + BKN - 1) / BKN)   // 391 buckets
#define CH  4096                     // edges per scatter block
#define NCHB ((NE + CH - 1) / CH)    // 391 scatter blocks
#define AGG_CAP 5120                 // max edges per bucket (mean 4096, sigma 64)

// ---------------- coarse bucket CSR ----------------

// per-block LDS-privatized histogram of buckets
__global__ __launch_bounds__(256) void bucket_count(const int* __restrict__ col,
                                                    int* __restrict__ gcnt) {
    __shared__ int h[NBK];
    int tid = threadIdx.x;
    for (int i = tid; i < NBK; i += 256) h[i] = 0;
    __syncthreads();
    int e0 = blockIdx.x * CH;
    #pragma unroll
    for (int i = 0; i < CH / 256; ++i) {
        int e = e0 + i * 256 + tid;
        if (e < NE) atomicAdd(&h[col[e] >> 8], 1);
    }
    __syncthreads();
    for (int i = tid; i < NBK; i += 256)
        if (h[i]) atomicAdd(&gcnt[i], h[i]);
}

// single block: exclusive scan of 391 bucket counts -> rowptrB, cursor
__global__ __launch_bounds__(512) void bucket_scan(const int* __restrict__ gcnt,
                                                   int* __restrict__ rowptrB,
                                                   int* __restrict__ gcur) {
    __shared__ int s[512];
    int t = threadIdx.x;
    int v = (t < NBK) ? gcnt[t] : 0;
    s[t] = v;
    __syncthreads();
    for (int d = 1; d < 512; d <<= 1) {
        int a = (t >= d) ? s[t - d] : 0;
        __syncthreads();
        s[t] += a;
        __syncthreads();
    }
    if (t < NBK) { int ex = s[t] - v; rowptrB[t] = ex; gcur[t] = ex; }
    if (t == 0) rowptrB[NBK] = NE;
}

// block bins CH edges by bucket in LDS, claims global space per bucket,
// writes bucket-sorted packed edges as contiguous runs.
// enc = (col & 255) << 24 | row      (row < 2^17)
__global__ __launch_bounds__(256) void bucket_scatter(const int* __restrict__ row,
                                                      const int* __restrict__ col,
                                                      int* __restrict__ gcur,
                                                      unsigned int* __restrict__ encs) {
    __shared__ int h[NBK];
    __shared__ int loff[NBK];
    __shared__ int cur[NBK];
    __shared__ int gbase[NBK];
    __shared__ unsigned int stage[CH];
    __shared__ unsigned short sbkt[CH];
    int tid = threadIdx.x;
    for (int i = tid; i < NBK; i += 256) h[i] = 0;
    __syncthreads();
    int e0 = blockIdx.x * CH;
    int nval = NE - e0; if (nval > CH) nval = CH;
    int c[16];
    #pragma unroll
    for (int i = 0; i < 16; ++i) {
        int e = e0 + i * 256 + tid;
        c[i] = (e < NE) ? col[e] : -1;
        if (c[i] >= 0) atomicAdd(&h[c[i] >> 8], 1);
    }
    __syncthreads();
    // exclusive scan of h[0..NBK) by wave 0 (7 elems/lane, 64*7=448 >= 391)
    if (tid < 64) {
        int lane = tid, base = lane * 7;
        int pre[7]; int sum = 0;
        #pragma unroll
        for (int j = 0; j < 7; ++j) {
            int idx = base + j;
            int x = (idx < NBK) ? h[idx] : 0;
            pre[j] = sum; sum += x;
        }
        int run = sum;
        #pragma unroll
        for (int d = 1; d < 64; d <<= 1) {
            int n = __shfl_up(run, d, 64);
            if (lane >= d) run += n;
        }
        int lex = run - sum;
        #pragma unroll
        for (int j = 0; j < 7; ++j) {
            int idx = base + j;
            if (idx < NBK) { loff[idx] = lex + pre[j]; cur[idx] = lex + pre[j]; }
        }
    }
    __syncthreads();
    // claim global space per bucket
    for (int i = tid; i < NBK; i += 256) {
        int cnt = h[i];
        gbase[i] = cnt ? atomicAdd(&gcur[i], cnt) : 0;
    }
    __syncthreads();
    // rank + stage bucket-sorted
    #pragma unroll
    for (int i = 0; i < 16; ++i) {
        int e = e0 + i * 256 + tid;
        if (e < NE) {
            int cc = c[i], b = cc >> 8;
            int r = atomicAdd(&cur[b], 1);
            stage[r] = ((unsigned int)(cc & 255) << 24) | (unsigned int)row[e];
            sbkt[r] = (unsigned short)b;
        }
    }
    __syncthreads();
    // linear write-out: consecutive slots of a bucket -> consecutive global addrs
    for (int s = tid; s < nval; s += 256) {
        int b = sbkt[s];
        encs[gbase[b] + (s - loff[b])] = stage[s];
    }
}

// exact per-node degree from bucket segment; emits dinv
__global__ __launch_bounds__(256) void deg_dinv(const unsigned int* __restrict__ encs,
                                                const int* __restrict__ rowptrB,
                                                float* __restrict__ dinv) {
    __shared__ int h[BKN];
    int b = blockIdx.x, tid = threadIdx.x;
    h[tid] = 0;
    __syncthreads();
    int s0 = rowptrB[b], s1 = rowptrB[b + 1];
    for (int s = s0 + tid; s < s1; s += 256)
        atomicAdd(&h[encs[s] >> 24], 1);
    __syncthreads();
    int g = b * BKN + tid;
    if (g < NN) dinv[g] = rsqrtf((float)(h[tid] + 1));   // +1 self loop
}

// ---------------- tiled fp32 GEMM ----------------
// Block: 64 rows x N cols. 256 threads as 16x16; each thread owns 4 rows x 4 cols.
// EPI==0: out[r][c] = acc * aux[r]   (aux = dinv)    EPI==1: out[r][c] = acc + aux[c]
template <int K, int N, int EPI>
__global__ __launch_bounds__(256) void gemm_tiled(const float* __restrict__ X,
                                                  const float* __restrict__ W,
                                                  const float* __restrict__ aux,
                                                  float* __restrict__ out) {
    constexpr int KT  = 64;
    constexpr int KTP = KT + 4;
    __shared__ float Xl[64 * KTP];
    __shared__ float Wl[KT * N + 64];
    int tid = threadIdx.x;
    int tr = tid >> 4, tc = tid & 15;
    int rbase = blockIdx.x * 64;
    float4 acc[4] = {};

    for (int kt = 0; kt < K; kt += KT) {
        int fid = tid;
        #pragma unroll
        for (int p = 0; p < 4; ++p, fid += 256) {
            int m = fid >> 4, k4 = fid & 15;
            int rr = rbase + m; if (rr >= NN) rr = NN - 1;
            float4 v = *(const float4*)(X + (size_t)rr * K + kt + k4 * 4);
            *(float4*)(Xl + m * KTP + k4 * 4) = v;
        }
        constexpr int NW4 = KT * N / 4;
        for (int f = tid; f < NW4; f += 256)
            ((float4*)Wl)[f] = *((const float4*)(W + (size_t)kt * N) + f);
        __syncthreads();

        #pragma unroll 2
        for (int k4 = 0; k4 < KT / 4; ++k4) {
            float4 xa[4], wa[4];
            #pragma unroll
            for (int i = 0; i < 4; ++i)
                xa[i] = *(const float4*)(Xl + (tr * 4 + i) * KTP + k4 * 4);
            #pragma unroll
            for (int j = 0; j < 4; ++j)
                wa[j] = *(const float4*)(Wl + (k4 * 4 + j) * N + tc * 4);
            #pragma unroll
            for (int i = 0; i < 4; ++i) {
                acc[i].x = fmaf(xa[i].x, wa[0].x, acc[i].x);
                acc[i].y = fmaf(xa[i].x, wa[0].y, acc[i].y);
                acc[i].z = fmaf(xa[i].x, wa[0].z, acc[i].z);
                acc[i].w = fmaf(xa[i].x, wa[0].w, acc[i].w);
                acc[i].x = fmaf(xa[i].y, wa[1].x, acc[i].x);
                acc[i].y = fmaf(xa[i].y, wa[1].y, acc[i].y);
                acc[i].z = fmaf(xa[i].y, wa[1].z, acc[i].z);
                acc[i].w = fmaf(xa[i].y, wa[1].w, acc[i].w);
                acc[i].x = fmaf(xa[i].z, wa[2].x, acc[i].x);
                acc[i].y = fmaf(xa[i].z, wa[2].y, acc[i].y);
                acc[i].z = fmaf(xa[i].z, wa[2].z, acc[i].z);
                acc[i].w = fmaf(xa[i].z, wa[2].w, acc[i].w);
                acc[i].x = fmaf(xa[i].w, wa[3].x, acc[i].x);
                acc[i].y = fmaf(xa[i].w, wa[3].y, acc[i].y);
                acc[i].z = fmaf(xa[i].w, wa[3].z, acc[i].z);
                acc[i].w = fmaf(xa[i].w, wa[3].w, acc[i].w);
            }
        }
        __syncthreads();
    }

    if (EPI == 0) {
        #pragma unroll
        for (int i = 0; i < 4; ++i) {
            int r = rbase + tr * 4 + i;
            if (r < NN) {
                float d = aux[r];
                float4 v = acc[i];
                v.x *= d; v.y *= d; v.z *= d; v.w *= d;
                *(float4*)(out + (size_t)r * N + tc * 4) = v;
            }
        }
    } else {
        if (tc * 4 < N) {
            float4 b = *(const float4*)(aux + tc * 4);
            #pragma unroll
            for (int i = 0; i < 4; ++i) {
                int r = rbase + tr * 4 + i;
                if (r < NN) {
                    float4 v = acc[i];
                    v.x += b.x; v.y += b.y; v.z += b.z; v.w += b.w;
                    *(float4*)(out + (size_t)r * N + tc * 4) = v;
                }
            }
        }
    }
}

// ---------------- aggregation (block = 256-node bucket) ----------------
// LDS: exact per-node segmentation of the bucket's edges, then float4 wave-gather.
// out[g] = relu(dinv[g] * (hs[g] + sum_{r in in(g)} hs[r]) + bias)
__global__ __launch_bounds__(1024) void aggregate_bucket(const float* __restrict__ hs,
                                                         const unsigned int* __restrict__ encs,
                                                         const int* __restrict__ rowptrB,
                                                         const float* __restrict__ dinv,
                                                         const float* __restrict__ bias,
                                                         float* __restrict__ out) {
    __shared__ int cnt[BKN];
    __shared__ int off[BKN];
    __shared__ int cur[BKN];
    __shared__ int srow[AGG_CAP];
    int b = blockIdx.x, tid = threadIdx.x;
    if (tid < BKN) cnt[tid] = 0;
    __syncthreads();
    int s0 = rowptrB[b], s1 = rowptrB[b + 1];
    int m = s1 - s0;                                    // <= AGG_CAP (binomial +16 sigma)
    for (int s = tid; s < m; s += 1024)
        atomicAdd(&cnt[encs[s0 + s] >> 24], 1);
    __syncthreads();
    // exclusive scan of cnt[0..256) by wave 0 (4 elems/lane)
    if (tid < 64) {
        int lane = tid;
        int x0 = cnt[lane * 4], x1 = cnt[lane * 4 + 1];
        int x2 = cnt[lane * 4 + 2], x3 = cnt[lane * 4 + 3];
        int sum = x0 + x1 + x2 + x3;
        int run = sum;
        #pragma unroll
        for (int d = 1; d < 64; d <<= 1) {
            int n = __shfl_up(run, d, 64);
            if (lane >= d) run += n;
        }
        int ex = run - sum;
        off[lane * 4] = ex;           cur[lane * 4] = ex;
        off[lane * 4 + 1] = ex + x0;  cur[lane * 4 + 1] = ex + x0;
        off[lane * 4 + 2] = ex + x0 + x1;      cur[lane * 4 + 2] = ex + x0 + x1;
        off[lane * 4 + 3] = ex + x0 + x1 + x2; cur[lane * 4 + 3] = ex + x0 + x1 + x2;
    }
    __syncthreads();
    for (int s = tid; s < m; s += 1024) {
        unsigned int e = encs[s0 + s];
        int n = e >> 24;
        int r = atomicAdd(&cur[n], 1);
        srow[r] = (int)(e & 0xFFFFFFu);
    }
    __syncthreads();
    // gather: 16 waves x 16 nodes; subgroup sg (16 lanes) handles edge e+sg via float4
    int wid = tid >> 6, lane = tid & 63;
    int sg = lane >> 4, sl = lane & 15;
    const float4* hs4 = (const float4*)hs;
    for (int k = 0; k < 16; ++k) {
        int n = wid * 16 + k;
        int g = b * BKN + n;
        if (g >= NN) break;
        float4 acc = make_float4(0.f, 0.f, 0.f, 0.f);
        if (sg == 0) acc = hs4[(size_t)g * 16 + sl];    // self loop
        int eb = off[n], ee = eb + cnt[n];
        for (int e = eb; e + sg < ee; e += 4) {
            int r = srow[e + sg];
            float4 v = hs4[(size_t)r * 16 + sl];
            acc.x += v.x; acc.y += v.y; acc.z += v.z; acc.w += v.w;
        }
        acc.x += __shfl_xor(acc.x, 16); acc.y += __shfl_xor(acc.y, 16);
        acc.z += __shfl_xor(acc.z, 16); acc.w += __shfl_xor(acc.w, 16);
        acc.x += __shfl_xor(acc.x, 32); acc.y += __shfl_xor(acc.y, 32);
        acc.z += __shfl_xor(acc.z, 32); acc.w += __shfl_xor(acc.w, 32);
        if (sg == 0) {
            float d = dinv[g];
            float4 bb = *(const float4*)(bias + sl * 4);
            float4 o;
            o.x = fmaxf(fmaf(acc.x, d, bb.x), 0.f);
            o.y = fmaxf(fmaf(acc.y, d, bb.y), 0.f);
            o.z = fmaxf(fmaf(acc.z, d, bb.z), 0.f);
            o.w = fmaxf(fmaf(acc.w, d, bb.w), 0.f);
            ((float4*)out)[(size_t)g * 16 + sl] = o;
        }
    }
}

// ---------------- launch ----------------

extern "C" void kernel_launch(void* const* d_in, const int* in_sizes, int n_in,
                              void* d_out, int out_size, void* d_ws, size_t ws_size,
                              hipStream_t stream) {
    const float* x  = (const float*)d_in[0];
    const int* ei   = (const int*)d_in[1];      // [2, NE]
    const int* row  = ei;
    const int* col  = ei + NE;
    const float* W1 = (const float*)d_in[2];
    const float* b1 = (const float*)d_in[3];
    const float* W2 = (const float*)d_in[4];
    const float* b2 = (const float*)d_in[5];
    const float* Wc = (const float*)d_in[6];
    const float* bc = (const float*)d_in[7];
    float* out = (float*)d_out;

    char* ws = (char*)d_ws;
    size_t off = 0;
    auto alloc = [&](size_t bytes) {
        void* p = ws + off;
        off = (off + bytes + 255) & ~(size_t)255;
        return p;
    };
    int*   gcnt    = (int*)alloc((size_t)NBK * 4);
    int*   rowptrB = (int*)alloc((size_t)(NBK + 1) * 4);
    int*   gcur    = (int*)alloc((size_t)NBK * 4);
    unsigned int* encs = (unsigned int*)alloc((size_t)NE * 4);
    float* dinv    = (float*)alloc((size_t)NN * 4);
    float* bufA    = (float*)alloc((size_t)NN * NH * 4);
    float* bufB    = (float*)alloc((size_t)NN * NH * 4);

    const int GB = (NN + 63) / 64;               // 1563

    hipMemsetAsync(gcnt, 0, (size_t)NBK * 4, stream);
    bucket_count<<<NCHB, 256, 0, stream>>>(col, gcnt);
    bucket_scan<<<1, 512, 0, stream>>>(gcnt, rowptrB, gcur);
    bucket_scatter<<<NCHB, 256, 0, stream>>>(row, col, gcur, encs);
    deg_dinv<<<NBK, 256, 0, stream>>>(encs, rowptrB, dinv);

    // layer 1: hs = (x @ W1) * dinv ; h1 = relu(dinv * agg + b1)
    gemm_tiled<NF, NH, 0><<<GB, 256, 0, stream>>>(x, W1, dinv, bufA);
    aggregate_bucket<<<NBK, 1024, 0, stream>>>(bufA, encs, rowptrB, dinv, b1, bufB);
    // layer 2
    gemm_tiled<NH, NH, 0><<<GB, 256, 0, stream>>>(bufB, W2, dinv, bufA);
    aggregate_bucket<<<NBK, 1024, 0, stream>>>(bufA, encs, rowptrB, dinv, b2, bufB);
    // classifier
    gemm_tiled<NH, NC, 1><<<GB, 256, 0, stream>>>(bufB, Wc, bc, out);
}

// Round 4
// 227.546 us; speedup vs baseline: 2.5023x; 1.0790x over previous
//
#include <hip/hip_runtime.h>

#define NN 100000      // nodes
#define NE 1600000     // edges
#define NF 128         // in features
#define NH 64          // hidden
#define NC 40          // classes

#define BKN 128                      // nodes per bucket
#define NBK ((NN + BKN - 1) / BKN)   // 782 buckets
#define CH  4096                     // edges per scatter block
#define NCHB ((NE + CH - 1) / CH)    // 391 scatter blocks
#define CAPB 2560                    // slots per bucket region (mean 2048, sigma 45)

// ---------------- coarse bucket CSR (fixed-capacity regions) ----------------

// block bins CH edges by bucket in LDS, claims space in each bucket's fixed
// region via atomicAdd(gcnt), writes bucket-sorted packed edges as runs.
// enc = (col & 127) << 24 | row      (row < 2^17)
__global__ __launch_bounds__(256) void bucket_scatter(const int* __restrict__ row,
                                                      const int* __restrict__ col,
                                                      int* __restrict__ gcnt,
                                                      unsigned int* __restrict__ encs) {
    __shared__ int h[NBK];
    __shared__ int loff[NBK];
    __shared__ int cur[NBK];
    __shared__ int gbase[NBK];
    __shared__ unsigned int stage[CH];
    __shared__ unsigned short sbkt[CH];
    int tid = threadIdx.x;
    for (int i = tid; i < NBK; i += 256) h[i] = 0;
    __syncthreads();
    int e0 = blockIdx.x * CH;
    int nval = NE - e0; if (nval > CH) nval = CH;
    int c[16];
    #pragma unroll
    for (int i = 0; i < 16; ++i) {
        int e = e0 + i * 256 + tid;
        c[i] = (e < NE) ? col[e] : -1;
        if (c[i] >= 0) atomicAdd(&h[c[i] >> 7], 1);
    }
    __syncthreads();
    // exclusive scan of h[0..NBK) by wave 0 (13 elems/lane, 64*13=832 >= 782)
    if (tid < 64) {
        int lane = tid, base = lane * 13;
        int pre[13]; int sum = 0;
        #pragma unroll
        for (int j = 0; j < 13; ++j) {
            int idx = base + j;
            int x = (idx < NBK) ? h[idx] : 0;
            pre[j] = sum; sum += x;
        }
        int run = sum;
        #pragma unroll
        for (int d = 1; d < 64; d <<= 1) {
            int n = __shfl_up(run, d, 64);
            if (lane >= d) run += n;
        }
        int lex = run - sum;
        #pragma unroll
        for (int j = 0; j < 13; ++j) {
            int idx = base + j;
            if (idx < NBK) { loff[idx] = lex + pre[j]; cur[idx] = lex + pre[j]; }
        }
    }
    __syncthreads();
    // claim global space per bucket
    for (int i = tid; i < NBK; i += 256) {
        int cnt = h[i];
        gbase[i] = cnt ? atomicAdd(&gcnt[i], cnt) : 0;
    }
    __syncthreads();
    // rank + stage bucket-sorted
    #pragma unroll
    for (int i = 0; i < 16; ++i) {
        int e = e0 + i * 256 + tid;
        if (e < NE) {
            int cc = c[i], b = cc >> 7;
            int r = atomicAdd(&cur[b], 1);
            stage[r] = ((unsigned int)(cc & 127) << 24) | (unsigned int)row[e];
            sbkt[r] = (unsigned short)b;
        }
    }
    __syncthreads();
    // linear write-out: consecutive slots of a bucket -> consecutive global addrs
    for (int s = tid; s < nval; s += 256) {
        int b = sbkt[s];
        encs[(size_t)b * CAPB + gbase[b] + (s - loff[b])] = stage[s];
    }
}

// exact per-node degree from bucket segment; emits deg + dinv
__global__ __launch_bounds__(BKN) void deg_dinv(const unsigned int* __restrict__ encs,
                                                const int* __restrict__ gcnt,
                                                int* __restrict__ deg,
                                                float* __restrict__ dinv) {
    __shared__ int h[BKN];
    int b = blockIdx.x, tid = threadIdx.x;
    h[tid] = 0;
    __syncthreads();
    int m = gcnt[b];
    const unsigned int* seg = encs + (size_t)b * CAPB;
    for (int s = tid; s < m; s += BKN)
        atomicAdd(&h[seg[s] >> 24], 1);
    __syncthreads();
    int g = b * BKN + tid;
    if (g < NN) {
        deg[g] = h[tid];
        dinv[g] = rsqrtf((float)(h[tid] + 1));   // +1 self loop
    }
}

// ---------------- tiled fp32 GEMM ----------------
// Block: 64 rows x N cols. 256 threads as 16x16; each thread owns 4 rows x 4 cols.
// EPI==0: out[r][c] = acc * aux[r]   (aux = dinv)    EPI==1: out[r][c] = acc + aux[c]
template <int K, int N, int EPI>
__global__ __launch_bounds__(256) void gemm_tiled(const float* __restrict__ X,
                                                  const float* __restrict__ W,
                                                  const float* __restrict__ aux,
                                                  float* __restrict__ out) {
    constexpr int KT  = 64;
    constexpr int KTP = KT + 4;
    __shared__ float Xl[64 * KTP];
    __shared__ float Wl[KT * N + 64];
    int tid = threadIdx.x;
    int tr = tid >> 4, tc = tid & 15;
    int rbase = blockIdx.x * 64;
    float4 acc[4] = {};

    for (int kt = 0; kt < K; kt += KT) {
        int fid = tid;
        #pragma unroll
        for (int p = 0; p < 4; ++p, fid += 256) {
            int m = fid >> 4, k4 = fid & 15;
            int rr = rbase + m; if (rr >= NN) rr = NN - 1;
            float4 v = *(const float4*)(X + (size_t)rr * K + kt + k4 * 4);
            *(float4*)(Xl + m * KTP + k4 * 4) = v;
        }
        constexpr int NW4 = KT * N / 4;
        for (int f = tid; f < NW4; f += 256)
            ((float4*)Wl)[f] = *((const float4*)(W + (size_t)kt * N) + f);
        __syncthreads();

        #pragma unroll 2
        for (int k4 = 0; k4 < KT / 4; ++k4) {
            float4 xa[4], wa[4];
            #pragma unroll
            for (int i = 0; i < 4; ++i)
                xa[i] = *(const float4*)(Xl + (tr * 4 + i) * KTP + k4 * 4);
            #pragma unroll
            for (int j = 0; j < 4; ++j)
                wa[j] = *(const float4*)(Wl + (k4 * 4 + j) * N + tc * 4);
            #pragma unroll
            for (int i = 0; i < 4; ++i) {
                acc[i].x = fmaf(xa[i].x, wa[0].x, acc[i].x);
                acc[i].y = fmaf(xa[i].x, wa[0].y, acc[i].y);
                acc[i].z = fmaf(xa[i].x, wa[0].z, acc[i].z);
                acc[i].w = fmaf(xa[i].x, wa[0].w, acc[i].w);
                acc[i].x = fmaf(xa[i].y, wa[1].x, acc[i].x);
                acc[i].y = fmaf(xa[i].y, wa[1].y, acc[i].y);
                acc[i].z = fmaf(xa[i].y, wa[1].z, acc[i].z);
                acc[i].w = fmaf(xa[i].y, wa[1].w, acc[i].w);
                acc[i].x = fmaf(xa[i].z, wa[2].x, acc[i].x);
                acc[i].y = fmaf(xa[i].z, wa[2].y, acc[i].y);
                acc[i].z = fmaf(xa[i].z, wa[2].z, acc[i].z);
                acc[i].w = fmaf(xa[i].z, wa[2].w, acc[i].w);
                acc[i].x = fmaf(xa[i].w, wa[3].x, acc[i].x);
                acc[i].y = fmaf(xa[i].w, wa[3].y, acc[i].y);
                acc[i].z = fmaf(xa[i].w, wa[3].z, acc[i].z);
                acc[i].w = fmaf(xa[i].w, wa[3].w, acc[i].w);
            }
        }
        __syncthreads();
    }

    if (EPI == 0) {
        #pragma unroll
        for (int i = 0; i < 4; ++i) {
            int r = rbase + tr * 4 + i;
            if (r < NN) {
                float d = aux[r];
                float4 v = acc[i];
                v.x *= d; v.y *= d; v.z *= d; v.w *= d;
                *(float4*)(out + (size_t)r * N + tc * 4) = v;
            }
        }
    } else {
        if (tc * 4 < N) {
            float4 b = *(const float4*)(aux + tc * 4);
            #pragma unroll
            for (int i = 0; i < 4; ++i) {
                int r = rbase + tr * 4 + i;
                if (r < NN) {
                    float4 v = acc[i];
                    v.x += b.x; v.y += b.y; v.z += b.z; v.w += b.w;
                    *(float4*)(out + (size_t)r * N + tc * 4) = v;
                }
            }
        }
    }
}

// ---------------- aggregation (block = 128-node bucket, 512 threads) ----------------
// Segment the bucket's edges by node in LDS (scan of deg + rank), then float4
// wave-gather with 2-deep unroll.
// out[g] = relu(dinv[g] * (hs[g] + sum_{r in in(g)} hs[r]) + bias)
__global__ __launch_bounds__(512) void aggregate_bucket(const float* __restrict__ hs,
                                                        const unsigned int* __restrict__ encs,
                                                        const int* __restrict__ gcnt,
                                                        const int* __restrict__ deg,
                                                        const float* __restrict__ dinv,
                                                        const float* __restrict__ bias,
                                                        float* __restrict__ out) {
    __shared__ int off[BKN + 1];
    __shared__ int cur[BKN];
    __shared__ int srow[CAPB];
    int b = blockIdx.x, tid = threadIdx.x;
    int m = gcnt[b];
    const unsigned int* seg = encs + (size_t)b * CAPB;
    // scan of deg -> off, cur (wave 0, 2 elems/lane)
    if (tid < 64) {
        int lane = tid;
        int g0 = b * BKN + lane * 2;
        int x0 = (g0 < NN) ? deg[g0] : 0;
        int x1 = (g0 + 1 < NN) ? deg[g0 + 1] : 0;
        int sum = x0 + x1, run = sum;
        #pragma unroll
        for (int d = 1; d < 64; d <<= 1) {
            int n = __shfl_up(run, d, 64);
            if (lane >= d) run += n;
        }
        int ex = run - sum;
        off[lane * 2] = ex;          cur[lane * 2] = ex;
        off[lane * 2 + 1] = ex + x0; cur[lane * 2 + 1] = ex + x0;
        if (lane == 63) off[BKN] = ex + x0 + x1;
    }
    __syncthreads();
    // rank: node-sorted edge list in LDS
    for (int s = tid; s < m; s += 512) {
        unsigned int e = seg[s];
        int n = e >> 24;
        int r = atomicAdd(&cur[n], 1);
        srow[r] = (int)(e & 0xFFFFFFu);
    }
    __syncthreads();
    // gather: 8 waves x 16 nodes; subgroup sg (16 lanes) takes edge e+sg, unroll 2
    int wid = tid >> 6, lane = tid & 63;
    int sg = lane >> 4, sl = lane & 15;
    const float4* hs4 = (const float4*)hs;
    #pragma unroll 1
    for (int k = 0; k < 16; ++k) {
        int n = wid * 16 + k;
        int g = b * BKN + n;
        if (g >= NN) break;
        float4 acc0 = make_float4(0.f, 0.f, 0.f, 0.f);
        float4 acc1 = make_float4(0.f, 0.f, 0.f, 0.f);
        if (sg == 0) acc0 = hs4[(size_t)g * 16 + sl];    // self loop
        int e = off[n], ee = off[n + 1];
        for (; e + 8 <= ee; e += 8) {
            int r0 = srow[e + sg];
            int r1 = srow[e + 4 + sg];
            float4 v0 = hs4[(size_t)r0 * 16 + sl];
            float4 v1 = hs4[(size_t)r1 * 16 + sl];
            acc0.x += v0.x; acc0.y += v0.y; acc0.z += v0.z; acc0.w += v0.w;
            acc1.x += v1.x; acc1.y += v1.y; acc1.z += v1.z; acc1.w += v1.w;
        }
        if (e + 4 <= ee) {
            int r = srow[e + sg];
            float4 v = hs4[(size_t)r * 16 + sl];
            acc0.x += v.x; acc0.y += v.y; acc0.z += v.z; acc0.w += v.w;
            e += 4;
        }
        if (e + sg < ee) {
            int r = srow[e + sg];
            float4 v = hs4[(size_t)r * 16 + sl];
            acc1.x += v.x; acc1.y += v.y; acc1.z += v.z; acc1.w += v.w;
        }
        acc0.x += acc1.x; acc0.y += acc1.y; acc0.z += acc1.z; acc0.w += acc1.w;
        acc0.x += __shfl_xor(acc0.x, 16); acc0.y += __shfl_xor(acc0.y, 16);
        acc0.z += __shfl_xor(acc0.z, 16); acc0.w += __shfl_xor(acc0.w, 16);
        acc0.x += __shfl_xor(acc0.x, 32); acc0.y += __shfl_xor(acc0.y, 32);
        acc0.z += __shfl_xor(acc0.z, 32); acc0.w += __shfl_xor(acc0.w, 32);
        if (sg == 0) {
            float d = dinv[g];
            float4 bb = *(const float4*)(bias + sl * 4);
            float4 o;
            o.x = fmaxf(fmaf(acc0.x, d, bb.x), 0.f);
            o.y = fmaxf(fmaf(acc0.y, d, bb.y), 0.f);
            o.z = fmaxf(fmaf(acc0.z, d, bb.z), 0.f);
            o.w = fmaxf(fmaf(acc0.w, d, bb.w), 0.f);
            ((float4*)out)[(size_t)g * 16 + sl] = o;
        }
    }
}

// ---------------- launch ----------------

extern "C" void kernel_launch(void* const* d_in, const int* in_sizes, int n_in,
                              void* d_out, int out_size, void* d_ws, size_t ws_size,
                              hipStream_t stream) {
    const float* x  = (const float*)d_in[0];
    const int* ei   = (const int*)d_in[1];      // [2, NE]
    const int* row  = ei;
    const int* col  = ei + NE;
    const float* W1 = (const float*)d_in[2];
    const float* b1 = (const float*)d_in[3];
    const float* W2 = (const float*)d_in[4];
    const float* b2 = (const float*)d_in[5];
    const float* Wc = (const float*)d_in[6];
    const float* bc = (const float*)d_in[7];
    float* out = (float*)d_out;

    char* ws = (char*)d_ws;
    size_t off = 0;
    auto alloc = [&](size_t bytes) {
        void* p = ws + off;
        off = (off + bytes + 255) & ~(size_t)255;
        return p;
    };
    int*   gcnt = (int*)alloc((size_t)NBK * 4);
    int*   deg  = (int*)alloc((size_t)NN * 4);
    float* dinv = (float*)alloc((size_t)NN * 4);
    unsigned int* encs = (unsigned int*)alloc((size_t)NBK * CAPB * 4);   // 8 MB
    float* bufA = (float*)alloc((size_t)NN * NH * 4);
    float* bufB = (float*)alloc((size_t)NN * NH * 4);

    const int GB = (NN + 63) / 64;               // 1563

    hipMemsetAsync(gcnt, 0, (size_t)NBK * 4, stream);
    bucket_scatter<<<NCHB, 256, 0, stream>>>(row, col, gcnt, encs);
    deg_dinv<<<NBK, BKN, 0, stream>>>(encs, gcnt, deg, dinv);

    // layer 1: hs = (x @ W1) * dinv ; h1 = relu(dinv * agg + b1)
    gemm_tiled<NF, NH, 0><<<GB, 256, 0, stream>>>(x, W1, dinv, bufA);
    aggregate_bucket<<<NBK, 512, 0, stream>>>(bufA, encs, gcnt, deg, dinv, b1, bufB);
    // layer 2
    gemm_tiled<NH, NH, 0><<<GB, 256, 0, stream>>>(bufB, W2, dinv, bufA);
    aggregate_bucket<<<NBK, 512, 0, stream>>>(bufA, encs, gcnt, deg, dinv, b2, bufB);
    // classifier
    gemm_tiled<NH, NC, 1><<<GB, 256, 0, stream>>>(bufB, Wc, bc, out);
}

// Round 5
// 191.303 us; speedup vs baseline: 2.9764x; 1.1895x over previous
//
#include <hip/hip_runtime.h>

#define NN 100000      // nodes
#define NE 1600000     // edges
#define NF 128         // in features
#define NH 64          // hidden
#define NC 40          // classes

#define BKN 128                      // nodes per bucket
#define NBK ((NN + BKN - 1) / BKN)   // 782 buckets
#define CH  4096                     // edges per scatter block
#define NCHB ((NE + CH - 1) / CH)    // 391 scatter blocks
#define CAPB 2560                    // slots per bucket region (mean 2048, sigma 45)

__device__ __forceinline__ unsigned short f2bf(float f) {
    unsigned int u = __builtin_bit_cast(unsigned int, f);
    u += 0x7FFFu + ((u >> 16) & 1u);          // round-to-nearest-even
    return (unsigned short)(u >> 16);
}
__device__ __forceinline__ float bf2f(unsigned short b) {
    unsigned int u = ((unsigned int)b) << 16;
    return __builtin_bit_cast(float, u);
}

// ---------------- coarse bucket CSR (fixed-capacity regions) ----------------

// block bins CH edges by bucket in LDS, claims space in each bucket's fixed
// region via atomicAdd(gcnt), writes bucket-sorted packed edges as runs.
// enc = (col & 127) << 24 | row      (row < 2^17)
__global__ __launch_bounds__(256) void bucket_scatter(const int* __restrict__ row,
                                                      const int* __restrict__ col,
                                                      int* __restrict__ gcnt,
                                                      unsigned int* __restrict__ encs) {
    __shared__ int h[NBK];
    __shared__ int loff[NBK];
    __shared__ int cur[NBK];
    __shared__ int gbase[NBK];
    __shared__ unsigned int stage[CH];
    __shared__ unsigned short sbkt[CH];
    int tid = threadIdx.x;
    for (int i = tid; i < NBK; i += 256) h[i] = 0;
    __syncthreads();
    int e0 = blockIdx.x * CH;
    int nval = NE - e0; if (nval > CH) nval = CH;
    int c[16];
    #pragma unroll
    for (int i = 0; i < 16; ++i) {
        int e = e0 + i * 256 + tid;
        c[i] = (e < NE) ? col[e] : -1;
        if (c[i] >= 0) atomicAdd(&h[c[i] >> 7], 1);
    }
    __syncthreads();
    // exclusive scan of h[0..NBK) by wave 0 (13 elems/lane, 64*13=832 >= 782)
    if (tid < 64) {
        int lane = tid, base = lane * 13;
        int pre[13]; int sum = 0;
        #pragma unroll
        for (int j = 0; j < 13; ++j) {
            int idx = base + j;
            int x = (idx < NBK) ? h[idx] : 0;
            pre[j] = sum; sum += x;
        }
        int run = sum;
        #pragma unroll
        for (int d = 1; d < 64; d <<= 1) {
            int n = __shfl_up(run, d, 64);
            if (lane >= d) run += n;
        }
        int lex = run - sum;
        #pragma unroll
        for (int j = 0; j < 13; ++j) {
            int idx = base + j;
            if (idx < NBK) { loff[idx] = lex + pre[j]; cur[idx] = lex + pre[j]; }
        }
    }
    __syncthreads();
    // claim global space per bucket
    for (int i = tid; i < NBK; i += 256) {
        int cnt = h[i];
        gbase[i] = cnt ? atomicAdd(&gcnt[i], cnt) : 0;
    }
    __syncthreads();
    // rank + stage bucket-sorted
    #pragma unroll
    for (int i = 0; i < 16; ++i) {
        int e = e0 + i * 256 + tid;
        if (e < NE) {
            int cc = c[i], b = cc >> 7;
            int r = atomicAdd(&cur[b], 1);
            stage[r] = ((unsigned int)(cc & 127) << 24) | (unsigned int)row[e];
            sbkt[r] = (unsigned short)b;
        }
    }
    __syncthreads();
    // linear write-out: consecutive slots of a bucket -> consecutive global addrs
    for (int s = tid; s < nval; s += 256) {
        int b = sbkt[s];
        encs[(size_t)b * CAPB + gbase[b] + (s - loff[b])] = stage[s];
    }
}

// exact per-node degree from bucket segment; emits deg + dinv
__global__ __launch_bounds__(BKN) void deg_dinv(const unsigned int* __restrict__ encs,
                                                const int* __restrict__ gcnt,
                                                int* __restrict__ deg,
                                                float* __restrict__ dinv) {
    __shared__ int h[BKN];
    int b = blockIdx.x, tid = threadIdx.x;
    h[tid] = 0;
    __syncthreads();
    int m = gcnt[b];
    const unsigned int* seg = encs + (size_t)b * CAPB;
    for (int s = tid; s < m; s += BKN)
        atomicAdd(&h[seg[s] >> 24], 1);
    __syncthreads();
    int g = b * BKN + tid;
    if (g < NN) {
        deg[g] = h[tid];
        dinv[g] = rsqrtf((float)(h[tid] + 1));   // +1 self loop
    }
}

// ---------------- tiled fp32 GEMM ----------------
// Block: 64 rows x N cols. 256 threads as 16x16; each thread owns 4 rows x 4 cols.
// EPI==0: hsb[r][c] = bf16(acc * aux[r])   (aux = dinv, pre-scaled bf16 table)
// EPI==1: outf[r][c] = acc + aux[c]        (aux = bias, classifier, fp32)
template <int K, int N, int EPI>
__global__ __launch_bounds__(256) void gemm_tiled(const float* __restrict__ X,
                                                  const float* __restrict__ W,
                                                  const float* __restrict__ aux,
                                                  float* __restrict__ outf,
                                                  unsigned short* __restrict__ hsb) {
    constexpr int KT  = 64;
    constexpr int KTP = KT + 4;
    __shared__ float Xl[64 * KTP];
    __shared__ float Wl[KT * N + 64];
    int tid = threadIdx.x;
    int tr = tid >> 4, tc = tid & 15;
    int rbase = blockIdx.x * 64;
    float4 acc[4] = {};

    for (int kt = 0; kt < K; kt += KT) {
        int fid = tid;
        #pragma unroll
        for (int p = 0; p < 4; ++p, fid += 256) {
            int m = fid >> 4, k4 = fid & 15;
            int rr = rbase + m; if (rr >= NN) rr = NN - 1;
            float4 v = *(const float4*)(X + (size_t)rr * K + kt + k4 * 4);
            *(float4*)(Xl + m * KTP + k4 * 4) = v;
        }
        constexpr int NW4 = KT * N / 4;
        for (int f = tid; f < NW4; f += 256)
            ((float4*)Wl)[f] = *((const float4*)(W + (size_t)kt * N) + f);
        __syncthreads();

        #pragma unroll 2
        for (int k4 = 0; k4 < KT / 4; ++k4) {
            float4 xa[4], wa[4];
            #pragma unroll
            for (int i = 0; i < 4; ++i)
                xa[i] = *(const float4*)(Xl + (tr * 4 + i) * KTP + k4 * 4);
            #pragma unroll
            for (int j = 0; j < 4; ++j)
                wa[j] = *(const float4*)(Wl + (k4 * 4 + j) * N + tc * 4);
            #pragma unroll
            for (int i = 0; i < 4; ++i) {
                acc[i].x = fmaf(xa[i].x, wa[0].x, acc[i].x);
                acc[i].y = fmaf(xa[i].x, wa[0].y, acc[i].y);
                acc[i].z = fmaf(xa[i].x, wa[0].z, acc[i].z);
                acc[i].w = fmaf(xa[i].x, wa[0].w, acc[i].w);
                acc[i].x = fmaf(xa[i].y, wa[1].x, acc[i].x);
                acc[i].y = fmaf(xa[i].y, wa[1].y, acc[i].y);
                acc[i].z = fmaf(xa[i].y, wa[1].z, acc[i].z);
                acc[i].w = fmaf(xa[i].y, wa[1].w, acc[i].w);
                acc[i].x = fmaf(xa[i].z, wa[2].x, acc[i].x);
                acc[i].y = fmaf(xa[i].z, wa[2].y, acc[i].y);
                acc[i].z = fmaf(xa[i].z, wa[2].z, acc[i].z);
                acc[i].w = fmaf(xa[i].z, wa[2].w, acc[i].w);
                acc[i].x = fmaf(xa[i].w, wa[3].x, acc[i].x);
                acc[i].y = fmaf(xa[i].w, wa[3].y, acc[i].y);
                acc[i].z = fmaf(xa[i].w, wa[3].z, acc[i].z);
                acc[i].w = fmaf(xa[i].w, wa[3].w, acc[i].w);
            }
        }
        __syncthreads();
    }

    if (EPI == 0) {
        #pragma unroll
        for (int i = 0; i < 4; ++i) {
            int r = rbase + tr * 4 + i;
            if (r < NN) {
                float d = aux[r];
                ushort4 o;
                o.x = f2bf(acc[i].x * d);
                o.y = f2bf(acc[i].y * d);
                o.z = f2bf(acc[i].z * d);
                o.w = f2bf(acc[i].w * d);
                *(ushort4*)(hsb + (size_t)r * N + tc * 4) = o;
            }
        }
    } else {
        if (tc * 4 < N) {
            float4 b = *(const float4*)(aux + tc * 4);
            #pragma unroll
            for (int i = 0; i < 4; ++i) {
                int r = rbase + tr * 4 + i;
                if (r < NN) {
                    float4 v = acc[i];
                    v.x += b.x; v.y += b.y; v.z += b.z; v.w += b.w;
                    *(float4*)(outf + (size_t)r * N + tc * 4) = v;
                }
            }
        }
    }
}

// ---------------- aggregation (block = 128-node bucket, 512 threads) ----------------
// Segment the bucket's edges by node in LDS (scan of deg + rank), then bf16
// wave-gather: subgroup of 16 lanes reads one 128B row (ushort4/lane), 4
// subgroups x unroll-4 = 16 edges / iteration, fp32 accumulate.
// out[g] = relu(dinv[g] * (hs[g] + sum_{r in in(g)} hs[r]) + bias)   [fp32 out]
__global__ __launch_bounds__(512) void aggregate_bucket(const unsigned short* __restrict__ hs,
                                                        const unsigned int* __restrict__ encs,
                                                        const int* __restrict__ gcnt,
                                                        const int* __restrict__ deg,
                                                        const float* __restrict__ dinv,
                                                        const float* __restrict__ bias,
                                                        float* __restrict__ out) {
    __shared__ int off[BKN + 1];
    __shared__ int cur[BKN];
    __shared__ int srow[CAPB];
    int b = blockIdx.x, tid = threadIdx.x;
    int m = gcnt[b];
    const unsigned int* seg = encs + (size_t)b * CAPB;
    // scan of deg -> off, cur (wave 0, 2 elems/lane)
    if (tid < 64) {
        int lane = tid;
        int g0 = b * BKN + lane * 2;
        int x0 = (g0 < NN) ? deg[g0] : 0;
        int x1 = (g0 + 1 < NN) ? deg[g0 + 1] : 0;
        int sum = x0 + x1, run = sum;
        #pragma unroll
        for (int d = 1; d < 64; d <<= 1) {
            int n = __shfl_up(run, d, 64);
            if (lane >= d) run += n;
        }
        int ex = run - sum;
        off[lane * 2] = ex;          cur[lane * 2] = ex;
        off[lane * 2 + 1] = ex + x0; cur[lane * 2 + 1] = ex + x0;
        if (lane == 63) off[BKN] = ex + x0 + x1;
    }
    __syncthreads();
    // rank: node-sorted edge list in LDS
    for (int s = tid; s < m; s += 512) {
        unsigned int e = seg[s];
        int n = e >> 24;
        int r = atomicAdd(&cur[n], 1);
        srow[r] = (int)(e & 0xFFFFFFu);
    }
    __syncthreads();
    // gather: 8 waves x 16 nodes
    int wid = tid >> 6, lane = tid & 63;
    int sg = lane >> 4, sl = lane & 15;
    const ushort4* hs4 = (const ushort4*)hs;     // row = 16 x ushort4 (128 B)
    #pragma unroll 1
    for (int k = 0; k < 16; ++k) {
        int n = wid * 16 + k;
        int g = b * BKN + n;
        if (g >= NN) break;
        float4 a0 = make_float4(0.f, 0.f, 0.f, 0.f);
        float4 a1 = make_float4(0.f, 0.f, 0.f, 0.f);
        float4 a2 = make_float4(0.f, 0.f, 0.f, 0.f);
        float4 a3 = make_float4(0.f, 0.f, 0.f, 0.f);
        if (sg == 0) {                           // self loop
            ushort4 s = hs4[(size_t)g * 16 + sl];
            a0.x += bf2f(s.x); a0.y += bf2f(s.y); a0.z += bf2f(s.z); a0.w += bf2f(s.w);
        }
        int e = off[n], ee = off[n + 1];
        for (; e + 16 <= ee; e += 16) {
            int r0 = srow[e + sg];
            int r1 = srow[e + 4 + sg];
            int r2 = srow[e + 8 + sg];
            int r3 = srow[e + 12 + sg];
            ushort4 v0 = hs4[(size_t)r0 * 16 + sl];
            ushort4 v1 = hs4[(size_t)r1 * 16 + sl];
            ushort4 v2 = hs4[(size_t)r2 * 16 + sl];
            ushort4 v3 = hs4[(size_t)r3 * 16 + sl];
            a0.x += bf2f(v0.x); a0.y += bf2f(v0.y); a0.z += bf2f(v0.z); a0.w += bf2f(v0.w);
            a1.x += bf2f(v1.x); a1.y += bf2f(v1.y); a1.z += bf2f(v1.z); a1.w += bf2f(v1.w);
            a2.x += bf2f(v2.x); a2.y += bf2f(v2.y); a2.z += bf2f(v2.z); a2.w += bf2f(v2.w);
            a3.x += bf2f(v3.x); a3.y += bf2f(v3.y); a3.z += bf2f(v3.z); a3.w += bf2f(v3.w);
        }
        for (; e + 4 <= ee; e += 4) {
            int r = srow[e + sg];
            ushort4 v = hs4[(size_t)r * 16 + sl];
            a1.x += bf2f(v.x); a1.y += bf2f(v.y); a1.z += bf2f(v.z); a1.w += bf2f(v.w);
        }
        if (e + sg < ee) {
            int r = srow[e + sg];
            ushort4 v = hs4[(size_t)r * 16 + sl];
            a2.x += bf2f(v.x); a2.y += bf2f(v.y); a2.z += bf2f(v.z); a2.w += bf2f(v.w);
        }
        a0.x += a1.x + a2.x + a3.x;
        a0.y += a1.y + a2.y + a3.y;
        a0.z += a1.z + a2.z + a3.z;
        a0.w += a1.w + a2.w + a3.w;
        a0.x += __shfl_xor(a0.x, 16); a0.y += __shfl_xor(a0.y, 16);
        a0.z += __shfl_xor(a0.z, 16); a0.w += __shfl_xor(a0.w, 16);
        a0.x += __shfl_xor(a0.x, 32); a0.y += __shfl_xor(a0.y, 32);
        a0.z += __shfl_xor(a0.z, 32); a0.w += __shfl_xor(a0.w, 32);
        if (sg == 0) {
            float d = dinv[g];
            float4 bb = *(const float4*)(bias + sl * 4);
            float4 o;
            o.x = fmaxf(fmaf(a0.x, d, bb.x), 0.f);
            o.y = fmaxf(fmaf(a0.y, d, bb.y), 0.f);
            o.z = fmaxf(fmaf(a0.z, d, bb.z), 0.f);
            o.w = fmaxf(fmaf(a0.w, d, bb.w), 0.f);
            ((float4*)out)[(size_t)g * 16 + sl] = o;
        }
    }
}

// ---------------- launch ----------------

extern "C" void kernel_launch(void* const* d_in, const int* in_sizes, int n_in,
                              void* d_out, int out_size, void* d_ws, size_t ws_size,
                              hipStream_t stream) {
    const float* x  = (const float*)d_in[0];
    const int* ei   = (const int*)d_in[1];      // [2, NE]
    const int* row  = ei;
    const int* col  = ei + NE;
    const float* W1 = (const float*)d_in[2];
    const float* b1 = (const float*)d_in[3];
    const float* W2 = (const float*)d_in[4];
    const float* b2 = (const float*)d_in[5];
    const float* Wc = (const float*)d_in[6];
    const float* bc = (const float*)d_in[7];
    float* out = (float*)d_out;

    char* ws = (char*)d_ws;
    size_t off = 0;
    auto alloc = [&](size_t bytes) {
        void* p = ws + off;
        off = (off + bytes + 255) & ~(size_t)255;
        return p;
    };
    int*   gcnt = (int*)alloc((size_t)NBK * 4);
    int*   deg  = (int*)alloc((size_t)NN * 4);
    float* dinv = (float*)alloc((size_t)NN * 4);
    unsigned int* encs = (unsigned int*)alloc((size_t)NBK * CAPB * 4);   // 8 MB
    unsigned short* hsb = (unsigned short*)alloc((size_t)NN * NH * 2);   // bf16 table
    float* bufB = (float*)alloc((size_t)NN * NH * 4);

    const int GB = (NN + 63) / 64;               // 1563

    hipMemsetAsync(gcnt, 0, (size_t)NBK * 4, stream);
    bucket_scatter<<<NCHB, 256, 0, stream>>>(row, col, gcnt, encs);
    deg_dinv<<<NBK, BKN, 0, stream>>>(encs, gcnt, deg, dinv);

    // layer 1: hsb = bf16((x @ W1) * dinv) ; h1 = relu(dinv * agg + b1)
    gemm_tiled<NF, NH, 0><<<GB, 256, 0, stream>>>(x, W1, dinv, nullptr, hsb);
    aggregate_bucket<<<NBK, 512, 0, stream>>>(hsb, encs, gcnt, deg, dinv, b1, bufB);
    // layer 2
    gemm_tiled<NH, NH, 0><<<GB, 256, 0, stream>>>(bufB, W2, dinv, nullptr, hsb);
    aggregate_bucket<<<NBK, 512, 0, stream>>>(hsb, encs, gcnt, deg, dinv, b2, bufB);
    // classifier
    gemm_tiled<NH, NC, 1><<<GB, 256, 0, stream>>>(bufB, Wc, bc, out, nullptr);
}

// Round 6
// 188.907 us; speedup vs baseline: 3.0142x; 1.0127x over previous
//
#include <hip/hip_runtime.h>

#define NN 100000      // nodes
#define NE 1600000     // edges
#define NF 128         // in features
#define NH 64          // hidden
#define NC 40          // classes

#define BKN 128                      // nodes per bucket
#define NBK ((NN + BKN - 1) / BKN)   // 782 buckets
#define CH  4096                     // edges per scatter block
#define NCHB ((NE + CH - 1) / CH)    // 391 scatter blocks
#define CAPB 2560                    // slots per bucket region (mean 2048, sigma 45)
#define OFFS (BKN + 1)

__device__ __forceinline__ unsigned short f2bf(float f) {
    unsigned int u = __builtin_bit_cast(unsigned int, f);
    u += 0x7FFFu + ((u >> 16) & 1u);          // round-to-nearest-even
    return (unsigned short)(u >> 16);
}
__device__ __forceinline__ float bf2f(unsigned short b) {
    unsigned int u = ((unsigned int)b) << 16;
    return __builtin_bit_cast(float, u);
}
__device__ __forceinline__ void bfacc(float4& a, ushort4 v) {
    a.x += bf2f(v.x); a.y += bf2f(v.y); a.z += bf2f(v.z); a.w += bf2f(v.w);
}

// ---------------- coarse bucket CSR (fixed-capacity regions) ----------------

// block bins CH edges by bucket in LDS, claims space in each bucket's fixed
// region via atomicAdd(gcnt), writes bucket-sorted packed edges as runs.
// enc = (col & 127) << 24 | row      (row < 2^17)
__global__ __launch_bounds__(256) void bucket_scatter(const int* __restrict__ row,
                                                      const int* __restrict__ col,
                                                      int* __restrict__ gcnt,
                                                      unsigned int* __restrict__ encs) {
    __shared__ int h[NBK];
    __shared__ int loff[NBK];
    __shared__ int cur[NBK];
    __shared__ int gbase[NBK];
    __shared__ unsigned int stage[CH];
    __shared__ unsigned short sbkt[CH];
    int tid = threadIdx.x;
    for (int i = tid; i < NBK; i += 256) h[i] = 0;
    __syncthreads();
    int e0 = blockIdx.x * CH;
    int nval = NE - e0; if (nval > CH) nval = CH;
    int c[16];
    #pragma unroll
    for (int i = 0; i < 16; ++i) {
        int e = e0 + i * 256 + tid;
        c[i] = (e < NE) ? col[e] : -1;
        if (c[i] >= 0) atomicAdd(&h[c[i] >> 7], 1);
    }
    __syncthreads();
    // exclusive scan of h[0..NBK) by wave 0 (13 elems/lane, 64*13=832 >= 782)
    if (tid < 64) {
        int lane = tid, base = lane * 13;
        int pre[13]; int sum = 0;
        #pragma unroll
        for (int j = 0; j < 13; ++j) {
            int idx = base + j;
            int x = (idx < NBK) ? h[idx] : 0;
            pre[j] = sum; sum += x;
        }
        int run = sum;
        #pragma unroll
        for (int d = 1; d < 64; d <<= 1) {
            int n = __shfl_up(run, d, 64);
            if (lane >= d) run += n;
        }
        int lex = run - sum;
        #pragma unroll
        for (int j = 0; j < 13; ++j) {
            int idx = base + j;
            if (idx < NBK) { loff[idx] = lex + pre[j]; cur[idx] = lex + pre[j]; }
        }
    }
    __syncthreads();
    // claim global space per bucket
    for (int i = tid; i < NBK; i += 256) {
        int cnt = h[i];
        gbase[i] = cnt ? atomicAdd(&gcnt[i], cnt) : 0;
    }
    __syncthreads();
    // rank + stage bucket-sorted
    #pragma unroll
    for (int i = 0; i < 16; ++i) {
        int e = e0 + i * 256 + tid;
        if (e < NE) {
            int cc = c[i], b = cc >> 7;
            int r = atomicAdd(&cur[b], 1);
            stage[r] = ((unsigned int)(cc & 127) << 24) | (unsigned int)row[e];
            sbkt[r] = (unsigned short)b;
        }
    }
    __syncthreads();
    // linear write-out: consecutive slots of a bucket -> consecutive global addrs
    for (int s = tid; s < nval; s += 256) {
        int b = sbkt[s];
        encs[(size_t)b * CAPB + gbase[b] + (s - loff[b])] = stage[s];
    }
}

// ---------------- csr_sort: node-sort each bucket IN PLACE, emit off + dinv ----------------
// After this, encs[b*CAPB ..] holds plain row indices, node-sorted; offg[b*OFFS+i]
// gives each node's segment. Runs once, reused by both aggregations.
__global__ __launch_bounds__(256) void csr_sort(unsigned int* __restrict__ encs,
                                                const int* __restrict__ gcnt,
                                                int* __restrict__ offg,
                                                float* __restrict__ dinv) {
    __shared__ unsigned int sseg[CAPB];
    __shared__ int h[BKN];
    __shared__ int off[OFFS];
    __shared__ int cur[BKN];
    int b = blockIdx.x, tid = threadIdx.x;
    if (tid < BKN) h[tid] = 0;
    __syncthreads();
    int m = gcnt[b];
    unsigned int* seg = encs + (size_t)b * CAPB;
    for (int s = tid; s < m; s += 256) {
        unsigned int e = seg[s];
        sseg[s] = e;
        atomicAdd(&h[e >> 24], 1);
    }
    __syncthreads();
    // dinv from exact degree
    if (tid < BKN) {
        int g = b * BKN + tid;
        if (g < NN) dinv[g] = rsqrtf((float)(h[tid] + 1));   // +1 self loop
    }
    // exclusive scan of h (wave 0, 2 elems/lane)
    if (tid < 64) {
        int lane = tid;
        int x0 = h[lane * 2], x1 = h[lane * 2 + 1];
        int sum = x0 + x1, run = sum;
        #pragma unroll
        for (int d = 1; d < 64; d <<= 1) {
            int n = __shfl_up(run, d, 64);
            if (lane >= d) run += n;
        }
        int ex = run - sum;
        off[lane * 2] = ex;          cur[lane * 2] = ex;
        off[lane * 2 + 1] = ex + x0; cur[lane * 2 + 1] = ex + x0;
        if (lane == 63) off[BKN] = run;
    }
    __syncthreads();
    // rank from LDS copy, write node-sorted row indices back in place
    for (int s = tid; s < m; s += 256) {
        unsigned int e = sseg[s];
        int n = e >> 24;
        int r = atomicAdd(&cur[n], 1);
        seg[r] = e & 0xFFFFFFu;
    }
    if (tid < OFFS) offg[b * OFFS + tid] = off[tid];
}

// ---------------- tiled fp32 GEMM ----------------
// Block: 64 rows x N cols. 256 threads as 16x16; each thread owns 4 rows x 4 cols.
// EPI==0: hsb[r][c] = bf16(acc * aux[r])   (aux = dinv, pre-scaled bf16 table)
// EPI==1: outf[r][c] = acc + aux[c]        (aux = bias, classifier, fp32)
template <int K, int N, int EPI>
__global__ __launch_bounds__(256) void gemm_tiled(const float* __restrict__ X,
                                                  const float* __restrict__ W,
                                                  const float* __restrict__ aux,
                                                  float* __restrict__ outf,
                                                  unsigned short* __restrict__ hsb) {
    constexpr int KT  = 64;
    constexpr int KTP = KT + 4;
    __shared__ float Xl[64 * KTP];
    __shared__ float Wl[KT * N + 64];
    int tid = threadIdx.x;
    int tr = tid >> 4, tc = tid & 15;
    int rbase = blockIdx.x * 64;
    float4 acc[4] = {};

    for (int kt = 0; kt < K; kt += KT) {
        int fid = tid;
        #pragma unroll
        for (int p = 0; p < 4; ++p, fid += 256) {
            int m = fid >> 4, k4 = fid & 15;
            int rr = rbase + m; if (rr >= NN) rr = NN - 1;
            float4 v = *(const float4*)(X + (size_t)rr * K + kt + k4 * 4);
            *(float4*)(Xl + m * KTP + k4 * 4) = v;
        }
        constexpr int NW4 = KT * N / 4;
        for (int f = tid; f < NW4; f += 256)
            ((float4*)Wl)[f] = *((const float4*)(W + (size_t)kt * N) + f);
        __syncthreads();

        #pragma unroll 2
        for (int k4 = 0; k4 < KT / 4; ++k4) {
            float4 xa[4], wa[4];
            #pragma unroll
            for (int i = 0; i < 4; ++i)
                xa[i] = *(const float4*)(Xl + (tr * 4 + i) * KTP + k4 * 4);
            #pragma unroll
            for (int j = 0; j < 4; ++j)
                wa[j] = *(const float4*)(Wl + (k4 * 4 + j) * N + tc * 4);
            #pragma unroll
            for (int i = 0; i < 4; ++i) {
                acc[i].x = fmaf(xa[i].x, wa[0].x, acc[i].x);
                acc[i].y = fmaf(xa[i].x, wa[0].y, acc[i].y);
                acc[i].z = fmaf(xa[i].x, wa[0].z, acc[i].z);
                acc[i].w = fmaf(xa[i].x, wa[0].w, acc[i].w);
                acc[i].x = fmaf(xa[i].y, wa[1].x, acc[i].x);
                acc[i].y = fmaf(xa[i].y, wa[1].y, acc[i].y);
                acc[i].z = fmaf(xa[i].y, wa[1].z, acc[i].z);
                acc[i].w = fmaf(xa[i].y, wa[1].w, acc[i].w);
                acc[i].x = fmaf(xa[i].z, wa[2].x, acc[i].x);
                acc[i].y = fmaf(xa[i].z, wa[2].y, acc[i].y);
                acc[i].z = fmaf(xa[i].z, wa[2].z, acc[i].z);
                acc[i].w = fmaf(xa[i].z, wa[2].w, acc[i].w);
                acc[i].x = fmaf(xa[i].w, wa[3].x, acc[i].x);
                acc[i].y = fmaf(xa[i].w, wa[3].y, acc[i].y);
                acc[i].z = fmaf(xa[i].w, wa[3].z, acc[i].z);
                acc[i].w = fmaf(xa[i].w, wa[3].w, acc[i].w);
            }
        }
        __syncthreads();
    }

    if (EPI == 0) {
        #pragma unroll
        for (int i = 0; i < 4; ++i) {
            int r = rbase + tr * 4 + i;
            if (r < NN) {
                float d = aux[r];
                ushort4 o;
                o.x = f2bf(acc[i].x * d);
                o.y = f2bf(acc[i].y * d);
                o.z = f2bf(acc[i].z * d);
                o.w = f2bf(acc[i].w * d);
                *(ushort4*)(hsb + (size_t)r * N + tc * 4) = o;
            }
        }
    } else {
        if (tc * 4 < N) {
            float4 b = *(const float4*)(aux + tc * 4);
            #pragma unroll
            for (int i = 0; i < 4; ++i) {
                int r = rbase + tr * 4 + i;
                if (r < NN) {
                    float4 v = acc[i];
                    v.x += b.x; v.y += b.y; v.z += b.z; v.w += b.w;
                    *(float4*)(outf + (size_t)r * N + tc * 4) = v;
                }
            }
        }
    }
}

// ---------------- aggregation: subgroup-per-node bf16 gather ----------------
// Block = 128-node bucket, 512 threads = 8 waves x 4 subgroups of 16 lanes.
// Subgroup owns one node: lane = feature quarter (ushort4 = 8B), walks the
// node's sorted edge list with 4 independent accumulators (4 loads in flight).
// No cross-lane reduction; every lane stores a useful float4.
// out[g] = relu(dinv[g] * (hs[g] + sum_{r in in(g)} hs[r]) + bias)   [fp32 out]
__global__ __launch_bounds__(512) void aggregate_bucket(const unsigned short* __restrict__ hs,
                                                        const int* __restrict__ srow,
                                                        const int* __restrict__ offg,
                                                        const float* __restrict__ dinv,
                                                        const float* __restrict__ bias,
                                                        float* __restrict__ out) {
    __shared__ int off[OFFS];
    int b = blockIdx.x, tid = threadIdx.x;
    if (tid < OFFS) off[tid] = offg[b * OFFS + tid];
    __syncthreads();
    int wid = tid >> 6, lane = tid & 63;
    int sg = lane >> 4, sl = lane & 15;
    const ushort4* hs4 = (const ushort4*)hs;     // row = 16 x ushort4 (128 B)
    const int* ptr = srow + (size_t)b * CAPB;
    #pragma unroll
    for (int k = 0; k < 4; ++k) {
        int n = k * 32 + wid * 4 + sg;
        int g = b * BKN + n;
        if (g < NN) {
            float4 a0 = make_float4(0.f, 0.f, 0.f, 0.f);
            float4 a1 = make_float4(0.f, 0.f, 0.f, 0.f);
            float4 a2 = make_float4(0.f, 0.f, 0.f, 0.f);
            float4 a3 = make_float4(0.f, 0.f, 0.f, 0.f);
            bfacc(a0, hs4[(size_t)g * 16 + sl]);           // self loop
            int eb = off[n], ee = off[n + 1];
            for (int e = eb; e < ee; e += 4) {
                int r0 = ptr[e];
                int r1 = (e + 1 < ee) ? ptr[e + 1] : r0;
                int r2 = (e + 2 < ee) ? ptr[e + 2] : r0;
                int r3 = (e + 3 < ee) ? ptr[e + 3] : r0;
                ushort4 v0 = hs4[(size_t)r0 * 16 + sl];
                ushort4 v1 = hs4[(size_t)r1 * 16 + sl];
                ushort4 v2 = hs4[(size_t)r2 * 16 + sl];
                ushort4 v3 = hs4[(size_t)r3 * 16 + sl];
                bfacc(a0, v0);
                if (e + 1 < ee) bfacc(a1, v1);
                if (e + 2 < ee) bfacc(a2, v2);
                if (e + 3 < ee) bfacc(a3, v3);
            }
            float d = dinv[g];
            float4 bb = *(const float4*)(bias + sl * 4);
            float4 t;
            t.x = a0.x + a1.x + a2.x + a3.x;
            t.y = a0.y + a1.y + a2.y + a3.y;
            t.z = a0.z + a1.z + a2.z + a3.z;
            t.w = a0.w + a1.w + a2.w + a3.w;
            float4 o;
            o.x = fmaxf(fmaf(t.x, d, bb.x), 0.f);
            o.y = fmaxf(fmaf(t.y, d, bb.y), 0.f);
            o.z = fmaxf(fmaf(t.z, d, bb.z), 0.f);
            o.w = fmaxf(fmaf(t.w, d, bb.w), 0.f);
            ((float4*)out)[(size_t)g * 16 + sl] = o;
        }
    }
}

// ---------------- launch ----------------

extern "C" void kernel_launch(void* const* d_in, const int* in_sizes, int n_in,
                              void* d_out, int out_size, void* d_ws, size_t ws_size,
                              hipStream_t stream) {
    const float* x  = (const float*)d_in[0];
    const int* ei   = (const int*)d_in[1];      // [2, NE]
    const int* row  = ei;
    const int* col  = ei + NE;
    const float* W1 = (const float*)d_in[2];
    const float* b1 = (const float*)d_in[3];
    const float* W2 = (const float*)d_in[4];
    const float* b2 = (const float*)d_in[5];
    const float* Wc = (const float*)d_in[6];
    const float* bc = (const float*)d_in[7];
    float* out = (float*)d_out;

    char* ws = (char*)d_ws;
    size_t off = 0;
    auto alloc = [&](size_t bytes) {
        void* p = ws + off;
        off = (off + bytes + 255) & ~(size_t)255;
        return p;
    };
    int*   gcnt = (int*)alloc((size_t)NBK * 4);
    int*   offg = (int*)alloc((size_t)NBK * OFFS * 4);
    float* dinv = (float*)alloc((size_t)NN * 4);
    unsigned int* encs = (unsigned int*)alloc((size_t)NBK * CAPB * 4);   // 8 MB
    unsigned short* hsb = (unsigned short*)alloc((size_t)NN * NH * 2);   // bf16 table
    float* bufB = (float*)alloc((size_t)NN * NH * 4);

    const int GB = (NN + 63) / 64;               // 1563

    hipMemsetAsync(gcnt, 0, (size_t)NBK * 4, stream);
    bucket_scatter<<<NCHB, 256, 0, stream>>>(row, col, gcnt, encs);
    csr_sort<<<NBK, 256, 0, stream>>>(encs, gcnt, offg, dinv);

    // layer 1: hsb = bf16((x @ W1) * dinv) ; h1 = relu(dinv * agg + b1)
    gemm_tiled<NF, NH, 0><<<GB, 256, 0, stream>>>(x, W1, dinv, nullptr, hsb);
    aggregate_bucket<<<NBK, 512, 0, stream>>>(hsb, (const int*)encs, offg, dinv, b1, bufB);
    // layer 2
    gemm_tiled<NH, NH, 0><<<GB, 256, 0, stream>>>(bufB, W2, dinv, nullptr, hsb);
    aggregate_bucket<<<NBK, 512, 0, stream>>>(hsb, (const int*)encs, offg, dinv, b2, bufB);
    // classifier
    gemm_tiled<NH, NC, 1><<<GB, 256, 0, stream>>>(bufB, Wc, bc, out, nullptr);
}